// Round 19
// baseline (245.047 us; speedup 1.0000x reference)
//
#include <hip/hip_runtime.h>
#include <hip/hip_bf16.h>
#include <string.h>

using bf16 = __hip_bfloat16;
typedef __attribute__((ext_vector_type(8))) short short8;   // 8 bf16 (4 VGPR)
typedef __attribute__((ext_vector_type(4))) short short4v;  // 4 bf16 (8 B)
typedef __attribute__((ext_vector_type(4))) float f32x4;

constexpr int BATCH = 32;
constexpr int INC = 3;
constexpr int OC = 64;
constexpr int HH = 64;
constexpr int WW = 64;
constexpr int KK = 5;
constexpr int HP = 32;
constexpr int WP = 32;
constexpr int NL = 16;
constexpr int LW = 128;
constexpr int OW = 100;

__device__ __forceinline__ short f2bs(float v) {
  bf16 h = __float2bfloat16(v);
  return *(short*)&h;
}

// 16B zero page: per-lane global source for halo/pad lanes of global_load_lds.
__device__ alignas(16) short zero16[16];

// ---------------- fused head kernel: scores + weight prep + x->bf16 pad + zeroing ----
// blocks [0,512): scores — 1 px/thread; 16 partial maxes per (d,b).
// blocks [512, 896): wA prep. blocks [896, 1152): wT prep (coalesced).
// blocks [1152, 1382): zero-padded bf16 image xb[b][ic][68][72].
// block 1382: zero out[] (3200 f32) + cnt[] (512 ints) — stream-ordered before conv2m.
__global__ __launch_bounds__(256) void k_head(
    const float* __restrict__ x, const float* __restrict__ nw,
    float* __restrict__ scores_p, const float* __restrict__ cw1,
    const float* __restrict__ cw2, short* __restrict__ wA,
    short* __restrict__ wT, short* __restrict__ xb, float* __restrict__ out,
    int* __restrict__ cnt) {
  int blk = blockIdx.x;
  int t = threadIdx.x;
  if (blk < 512) {
    int b = blk & 31, g = blk >> 5;  // g 0..15: rows 4g..4g+3
    __shared__ float wsm[4][80];
    __shared__ alignas(16) f32x4 red4[256];
    for (int i = t; i < 300; i += 256) {
      int d = i / 75, k = i - 75 * d;
      int f = (2 << d) - 2;  // filters 0,2,6,14
      wsm[d][k] = nw[f * 75 + k];
    }
    __syncthreads();
    int p = g * 256 + t;
    int y = p >> 6, xx = p & 63;
    f32x4 s = f32x4{0.f, 0.f, 0.f, 0.f};
    for (int ic = 0; ic < INC; ic++) {
      for (int ky = 0; ky < KK; ky++) {
        int yy = y + ky - 2;
        if (yy < 0 || yy >= HH) continue;
        const float* xr = x + ((b * INC + ic) * HH + yy) * WW;
        int wk = (ic * KK + ky) * KK;
        for (int kx = 0; kx < KK; kx++) {
          int xc = xx + kx - 2;
          if (xc < 0 || xc >= WW) continue;
          float xv = xr[xc];
          s[0] = fmaf(xv, wsm[0][wk + kx], s[0]);
          s[1] = fmaf(xv, wsm[1][wk + kx], s[1]);
          s[2] = fmaf(xv, wsm[2][wk + kx], s[2]);
          s[3] = fmaf(xv, wsm[3][wk + kx], s[3]);
        }
      }
    }
    red4[t] = s;
    __syncthreads();
    for (int s2 = 128; s2 > 0; s2 >>= 1) {
      if (t < s2) {
        f32x4 a = red4[t], c = red4[t + s2];
#pragma unroll
        for (int d = 0; d < 4; d++) a[d] = fmaxf(a[d], c[d]);
        red4[t] = a;
      }
      __syncthreads();
    }
    if (t == 0) {
      f32x4 r = red4[0];
#pragma unroll
      for (int d = 0; d < 4; d++) scores_p[(d * BATCH + b) * 16 + g] = r[d];
    }
  } else if (blk < 896) {
    int idx = (blk - 512) * 256 + t;
    if (idx < 98304) {
      int k = idx % 96;
      int rem = idx / 96;  // l*64 + oc
      float v = (k < 75) ? cw1[(size_t)rem * 75 + k] : 0.f;
      wA[(size_t)rem * 96 + k] = f2bs(v);
    }
  } else if (blk < 1152) {
    int i3 = (blk - 896) * 256 + t;   // < 65536: (l, oc, ic)
    int l = i3 >> 12;
    int oc = (i3 >> 6) & 63;
    int ic = i3 & 63;
    const float* src = cw2 + (size_t)((l * OC + oc) * OC + ic) * 25;
    short* dst = wT + (size_t)oc * 64 + ic;
#pragma unroll
    for (int tap = 0; tap < 25; tap++)
      dst[((size_t)(l * 25 + tap)) * 4096] = f2bs(src[tap]);
  } else if (blk < 1382) {
    // pad+convert: job -> (img = b*3+ic, padded row 0..67, 8-short segment 0..8)
    int job = (blk - 1152) * 256 + t;
    if (job < 58752) {  // 96 * 68 * 9
      int seg = job % 9;
      int rem = job / 9;
      int row = rem % 68;
      int img = rem / 68;
      int gy = row - 2;
      short8 v;
#pragma unroll
      for (int j = 0; j < 8; j++) {
        int gx = seg * 8 + j - 2;
        float f = (gy >= 0 && gy < HH && gx >= 0 && gx < WW)
                      ? x[((size_t)img * HH + gy) * WW + gx] : 0.f;
        v[j] = f2bs(f);
      }
      *(short8*)(xb + ((size_t)img * 68 + row) * 72 + seg * 8) = v;
    }
  } else {
    for (int i = t; i < BATCH * OW; i += 256) out[i] = 0.f;
    for (int i = t; i < NL * BATCH; i += 256) cnt[i] = 0;
  }
}

// ---------------- conv1 via im2col + MFMA + in-register maxpool/relu -> h1t ----------------
// R29 version (verified): leaf-invariant B-fragments hoisted to 24 short8 regs;
// barrier-free shuffle epilogue.
__device__ __forceinline__ int slotbase(int col) {
  return col * 104 + 8 * ((-(col >> 1)) & 7);
}

__global__ __launch_bounds__(256, 2) void k_conv1m(
    const short* __restrict__ xb, const short* __restrict__ wA,
    short* __restrict__ h1t) {
  constexpr int BSZ = 64 * 104 + 64;
  __shared__ alignas(16) short Bm[2 * BSZ];
  int bid = blockIdx.x;
  int py = bid & 31;
  int b = bid >> 5;
  int t = threadIdx.x;
  int w = t >> 6, lane = t & 63;
  int n = lane & 15, q = lane >> 4;

  for (int i = t; i < BSZ; i += 256) ((int*)Bm)[i] = 0;
  __syncthreads();
  for (int i = t; i < 1200; i += 256) {
    int cg = i & 7;
    int kk = (i >> 3) % 75;
    int dy = (i >> 3) / 75;
    int ic = kk / 25, r25 = kk % 25;
    int ky = r25 / 5, kx = r25 % 5;
    int y = 2 * py + dy + ky;   // padded row index (halo folded in)
    const short* xr = xb + ((size_t)(b * INC + ic) * 68 + y) * 72 + kx;
    short* dst = Bm + dy * BSZ;
#pragma unroll
    for (int c8 = 0; c8 < 8; c8++) {
      int c = cg * 8 + c8;
      dst[slotbase(c) + kk] = xr[c];   // in-bounds by construction
    }
  }
  __syncthreads();   // last barrier in the kernel

  // hoist the 24 leaf-invariant B-fragments into registers (compile-time indices)
  short8 Breg[2][2][2][3];  // [dy][dx][h][ks]
#pragma unroll
  for (int dy = 0; dy < 2; dy++)
#pragma unroll
    for (int dx = 0; dx < 2; dx++)
#pragma unroll
      for (int h = 0; h < 2; h++) {
        int col = 2 * (h * 16 + n) + dx;
        const short* bp = Bm + dy * BSZ + slotbase(col);
#pragma unroll
        for (int ks = 0; ks < 3; ks++)
          Breg[dy][dx][h][ks] = *(const short8*)(bp + ks * 32 + q * 8);
      }

  short8 Acur[3], Anx[3];
#pragma unroll
  for (int ks = 0; ks < 3; ks++)
    Anx[ks] = *(const short8*)(wA + ((size_t)(w * 16 + n) * 96) + ks * 32 + q * 8);

  short* hb = h1t + ((size_t)b * (HP * WP) + py * WP) * OC;

  for (int l = 0; l < NL; l++) {
#pragma unroll
    for (int ks = 0; ks < 3; ks++) Acur[ks] = Anx[ks];
    if (l < NL - 1) {
#pragma unroll
      for (int ks = 0; ks < 3; ks++)
        Anx[ks] = *(const short8*)(wA + ((size_t)((l + 1) * OC + w * 16 + n) * 96) +
                                   ks * 32 + q * 8);
    }
    f32x4 acc[2][2][2];  // [dy][dx][half]
#pragma unroll
    for (int dy = 0; dy < 2; dy++)
#pragma unroll
      for (int dx = 0; dx < 2; dx++)
#pragma unroll
        for (int h = 0; h < 2; h++) acc[dy][dx][h] = f32x4{0.f, 0.f, 0.f, 0.f};

#pragma unroll
    for (int dy = 0; dy < 2; dy++)
#pragma unroll
      for (int dx = 0; dx < 2; dx++)
#pragma unroll
        for (int h = 0; h < 2; h++)
#pragma unroll
          for (int ks = 0; ks < 3; ks++)
            acc[dy][dx][h] = __builtin_amdgcn_mfma_f32_16x16x32_bf16(
                Acur[ks], Breg[dy][dx][h][ks], acc[dy][dx][h], 0, 0, 0);

    // barrier-free epilogue: pool+relu -> bf16 quads for h=0,1
    short4v sv0, sv1;
#pragma unroll
    for (int r = 0; r < 4; r++) {
      float v0 = fmaxf(fmaxf(acc[0][0][0][r], acc[0][1][0][r]),
                       fmaxf(acc[1][0][0][r], acc[1][1][0][r]));
      sv0[r] = f2bs(fmaxf(v0, 0.f));
      float v1 = fmaxf(fmaxf(acc[0][0][1][r], acc[0][1][1][r]),
                       fmaxf(acc[1][0][1][r], acc[1][1][1][r]));
      sv1[r] = f2bs(fmaxf(v1, 0.f));
    }
    long long l0, l1;
    memcpy(&l0, &sv0, 8);
    memcpy(&l1, &sv1, 8);
    bool hodd = (q & 1);                     // this lane keeps h = q&1
    long long own = hodd ? l1 : l0;
    long long oth = hodd ? l0 : l1;          // send the other-h payload
    long long rec = __shfl_xor(oth, 16, 64); // partner q^1's h=q&1 payload
    long long lo = hodd ? rec : own;         // even q owns the lower oc quad
    long long hi = hodd ? own : rec;
    union { short8 s; long long ll[2]; } u;
    u.ll[0] = lo; u.ll[1] = hi;
    int px = ((q & 1) << 4) + n;
    *(short8*)(hb + ((size_t)l * BATCH * (HP * WP)) * OC + (size_t)px * OC +
               16 * w + 8 * (q >> 1)) = u.s;
  }
}

// ---------------- conv2 + spatial max + (last-block) fused MLP/combine ----------------
// conv2 core is R20 VERBATIM (117 us, 0 conflicts — its measured ceiling).
// R31: each block writes its pfeat half, device-fences, bumps cnt[l*B+b];
// the SECOND block of the pair re-fences (acquire) and runs the (l,b) MLP inline,
// reusing the dead hs LDS. Most MLP instances hide under still-running conv2m
// blocks; the k_mlp launch disappears. MLP accumulations use 4-way partial sums
// (the old k_mlp was a 192-deep dependent fma chain = latency-bound).
__global__ __launch_bounds__(256, 2) void k_conv2m(
    const short* __restrict__ h1t, const short* __restrict__ wT,
    float* __restrict__ pfeat, const float* __restrict__ w1s,
    const float* __restrict__ b1s, const float* __restrict__ w2s,
    const float* __restrict__ b2s, const float* __restrict__ scores_p,
    const float* __restrict__ nb, float* __restrict__ out,
    int* __restrict__ cnt) {
  constexpr int CS2 = 32;          // shorts per (row,col) slot: 32 ic of chunk (64 B)
  __shared__ alignas(16) short hs[23040];     // 20 rows x 36 cols x 32 ic = 46,080 B
  __shared__ alignas(16) float sred[4][64];
  __shared__ int flag;
  int raw = blockIdx.x;
  int bid = (raw & 7) * 128 + (raw >> 3);  // XCD swizzle (bijective: 1024/8=128)
  int half = bid & 1;
  int b = (bid >> 1) & 31;
  int l = bid >> 6;
  int t = threadIdx.x;
  int w = t >> 6, lane = t & 63;
  int n = lane & 15, q = lane >> 4;
  int y0 = half * 16;
  const short* hg = h1t + (size_t)(l * BATCH + b) * (HP * WP) * OC;
  const short* wbase = wT + (size_t)l * 25 * OC * OC;

  // per-thread staging source offsets (granule idx = i*256+t < 2880), reused per chunk.
  // Store swizzle: granule (slot, v) sources icq = (v - (cc>>1)) & 3.
  int ofsB[12];
#pragma unroll
  for (int i = 0; i < 12; i++) {
    int idx = i * 256 + t;
    int v = idx & 3;
    int cc = (idx >> 2) % 36;
    int r = (idx >> 2) / 36;          // < 20 for idx < 2880
    int icq = (v - (cc >> 1)) & 3;
    int y = y0 - 2 + r, xx = cc - 2;
    bool ok = (y >= 0) && (y < HP) && (xx >= 0) && (xx < WP);
    ofsB[i] = ok ? ((y * WP + xx) * OC + icq * 8) : -1;
  }

  f32x4 acc[4][8];  // [octile][pxtile: row(4) x colhalf(2)]
#pragma unroll
  for (int i = 0; i < 4; i++)
#pragma unroll
    for (int j = 0; j < 8; j++) acc[i][j] = f32x4{0.f, 0.f, 0.f, 0.f};

  short8 Acur[4], Anext[4];
  // A-frag: A[m=lane&15][k=q*8+j]; k = ic within current 32-chunk
#pragma unroll
  for (int oct = 0; oct < 4; oct++)
    Anext[oct] = *(const short8*)(wbase + (size_t)(oct * 16 + n) * OC + q * 8);

  for (int chunk = 0; chunk < 2; chunk++) {
    __syncthreads();  // protect hs from previous chunk's readers
    // stage: 2880 granules of 16 B via global_load_lds (linear dest, swizzled source)
#pragma unroll
    for (int i = 0; i < 12; i++) {
      if (i < 11 || t < 64) {  // idx < 2880 only
        const short* gp = (ofsB[i] < 0) ? zero16 : (hg + ofsB[i] + chunk * 32);
        __builtin_amdgcn_global_load_lds(
            (const __attribute__((address_space(1))) void*)gp,
            (__attribute__((address_space(3))) void*)&hs[(i * 256 + t) * 8],
            16, 0, 0);
      }
    }
    __syncthreads();  // compiler drains vmcnt before the barrier

    for (int tap = 0; tap < 25; tap++) {
#pragma unroll
      for (int i = 0; i < 4; i++) Acur[i] = Anext[i];
      if (!(chunk == 1 && tap == 24)) {
        int ntap = tap + 1, nch = chunk;
        if (ntap == 25) { ntap = 0; nch = 1; }
        const short* tb = wbase + (size_t)ntap * OC * OC;
#pragma unroll
        for (int oct = 0; oct < 4; oct++)
          Anext[oct] = *(const short8*)(tb + (size_t)(oct * 16 + n) * OC +
                                        nch * 32 + q * 8);
      }
      int dy = tap / 5, dx = tap - 5 * dy;
      __builtin_amdgcn_s_setprio(1);
#pragma unroll
      for (int pxt = 0; pxt < 8; pxt++) {
        int lr = 4 * w + (pxt >> 1) + dy;     // slab row 0..19
        int c = (pxt & 1) * 16 + n + dx;      // slab col 0..35
        int v = (q + (c >> 1)) & 3;           // swizzled granule within slot
        short8 B = *(const short8*)(&hs[(lr * 36 + c) * CS2 + v * 8]);
#pragma unroll
        for (int oct = 0; oct < 4; oct++)
          acc[oct][pxt] = __builtin_amdgcn_mfma_f32_16x16x32_bf16(
              Acur[oct], B, acc[oct][pxt], 0, 0, 0);
      }
      __builtin_amdgcn_s_setprio(0);
    }
  }

  // epilogue: max over this wave's 128 px; D layout: col(px)=lane&15, row(oc)=q*4+reg
#pragma unroll
  for (int oct = 0; oct < 4; oct++) {
    f32x4 m = acc[oct][0];
#pragma unroll
    for (int pxt = 1; pxt < 8; pxt++)
#pragma unroll
      for (int r = 0; r < 4; r++) m[r] = fmaxf(m[r], acc[oct][pxt][r]);
#pragma unroll
    for (int mask = 1; mask <= 8; mask <<= 1)
#pragma unroll
      for (int r = 0; r < 4; r++) m[r] = fmaxf(m[r], __shfl_xor(m[r], mask, 64));
    if (n == 0) *(f32x4*)&sred[w][oct * 16 + q * 4] = m;
  }
  __syncthreads();
  if (t < 64) {
    float m = fmaxf(fmaxf(sred[0][t], sred[1][t]), fmaxf(sred[2][t], sred[3][t]));
    pfeat[((size_t)(l * BATCH + b) * 2 + half) * OC + t] = m;
  }
  // ---- last-block-wins fused MLP+combine for this (l, b) ----
  __threadfence();                        // release: pfeat half visible device-wide
  if (t == 0) flag = atomicAdd(&cnt[l * BATCH + b], 1);
  __syncthreads();
  if (flag == 1) {
    __threadfence();                      // acquire: partner's pfeat half visible
    float* fsh = (float*)hs;              // fs = fsh[0..63], hid = fsh[64..191]
    if (t < OC) {
      const float* pf = pfeat + (size_t)(l * BATCH + b) * 2 * OC;
      fsh[t] = fmaxf(fmaxf(pf[t], pf[OC + t]), 0.f);  // relu(global max)
    }
    __syncthreads();
    if (t < LW) {
      float h0 = b1s[l * LW + t], h1 = 0.f, h2 = 0.f, h3 = 0.f;
      const float* wb1 = w1s + (size_t)l * OC * LW + t;
      for (int c = 0; c < OC; c += 4) {
        h0 = fmaf(fsh[c + 0], wb1[(c + 0) * LW], h0);
        h1 = fmaf(fsh[c + 1], wb1[(c + 1) * LW], h1);
        h2 = fmaf(fsh[c + 2], wb1[(c + 2) * LW], h2);
        h3 = fmaf(fsh[c + 3], wb1[(c + 3) * LW], h3);
      }
      fsh[64 + t] = (h0 + h1) + (h2 + h3);
    }
    __syncthreads();
    if (t < OW) {
      // mix weight for (b, l) — 16 fmax + 4 sigmoid, redundant per thread
      float mix = 1.f;
#pragma unroll
      for (int d = 0; d < 4; d++) {
        const float* sp = scores_p + (d * BATCH + b) * 16;
        float sc = sp[0];
#pragma unroll
        for (int g = 1; g < 16; g++) sc = fmaxf(sc, sp[g]);
        int j = l >> (3 - d);
        int i = j >> 1;
        int bit = j & 1;
        float z = sc + nb[(1 << d) - 1 + i];
        float be = 1.f / (1.f + expf(-z));
        mix *= bit ? be : (1.f - be);
      }
      float o0 = b2s[l * OW + t], o1 = 0.f, o2 = 0.f, o3 = 0.f;
      const float* wb2 = w2s + (size_t)l * LW * OW + t;
      for (int j = 0; j < LW; j += 4) {
        o0 = fmaf(fsh[64 + j + 0], wb2[(j + 0) * OW], o0);
        o1 = fmaf(fsh[64 + j + 1], wb2[(j + 1) * OW], o1);
        o2 = fmaf(fsh[64 + j + 2], wb2[(j + 2) * OW], o2);
        o3 = fmaf(fsh[64 + j + 3], wb2[(j + 3) * OW], o3);
      }
      atomicAdd(&out[b * OW + t], mix * ((o0 + o1) + (o2 + o3)));
    }
  }
}

extern "C" void kernel_launch(void* const* d_in, const int* in_sizes, int n_in,
                              void* d_out, int out_size, void* d_ws, size_t ws_size,
                              hipStream_t stream) {
  const float* x   = (const float*)d_in[0];
  const float* nw  = (const float*)d_in[1];
  const float* nb  = (const float*)d_in[2];
  const float* cw1 = (const float*)d_in[3];
  const float* cw2 = (const float*)d_in[4];
  const float* w1s = (const float*)d_in[5];
  const float* b1s = (const float*)d_in[6];
  const float* w2s = (const float*)d_in[7];
  const float* b2s = (const float*)d_in[8];
  float* out = (float*)d_out;

  char* ws = (char*)d_ws;
  short* h1t = (short*)ws;  // [l,b][px 1024][ic 64] bf16 = 67.1 MB
  size_t off = (size_t)NL * BATCH * HP * WP * OC * sizeof(short);
  short* wT = (short*)(ws + off); off += (size_t)NL * 25 * OC * OC * sizeof(short);
  short* wA = (short*)(ws + off); off += (size_t)NL * OC * 96 * sizeof(short);
  short* xb = (short*)(ws + off); off += (size_t)96 * 68 * 72 * sizeof(short);
  float* scores_p = (float*)(ws + off); off += 4 * BATCH * 16 * sizeof(float);
  float* pfeat  = (float*)(ws + off); off += (size_t)NL * BATCH * 2 * OC * sizeof(float);
  int* cnt = (int*)(ws + off); off += NL * BATCH * sizeof(int);
  (void)ws_size; (void)in_sizes; (void)n_in; (void)out_size;

  k_head<<<1383, 256, 0, stream>>>(x, nw, scores_p, cw1, cw2, wA, wT, xb, out, cnt);
  k_conv1m<<<BATCH * 32, 256, 0, stream>>>(xb, wA, h1t);
  k_conv2m<<<NL * BATCH * 2, 256, 0, stream>>>(h1t, wT, pfeat, w1s, b1s, w2s, b2s,
                                               scores_p, nb, out, cnt);
}

// Round 20
// 154.838 us; speedup vs baseline: 1.5826x; 1.5826x over previous
//
#include <hip/hip_runtime.h>
#include <hip/hip_bf16.h>
#include <string.h>

using bf16 = __hip_bfloat16;
typedef __attribute__((ext_vector_type(8))) short short8;   // 8 bf16 (4 VGPR)
typedef __attribute__((ext_vector_type(4))) short short4v;  // 4 bf16 (8 B)
typedef __attribute__((ext_vector_type(4))) float f32x4;

constexpr int BATCH = 32;
constexpr int INC = 3;
constexpr int OC = 64;
constexpr int HH = 64;
constexpr int WW = 64;
constexpr int KK = 5;
constexpr int HP = 32;
constexpr int WP = 32;
constexpr int NL = 16;
constexpr int LW = 128;
constexpr int OW = 100;

__device__ __forceinline__ short f2bs(float v) {
  bf16 h = __float2bfloat16(v);
  return *(short*)&h;
}

// 16B zero page: per-lane global source for halo/pad lanes of global_load_lds.
__device__ alignas(16) short zero16[16];

// ---------------- fused head kernel: scores + weight prep + x->bf16 pad + out-zero ----
// blocks [0,512): scores — 1 px/thread; 16 partial maxes per (d,b).
// blocks [512, 896): wA prep. blocks [896, 1152): wT prep (coalesced).
// blocks [1152, 1382): zero-padded bf16 image xb[b][ic][68][72].
// block 1382: zero out[] (3200 f32) — ordered before k_mlp's atomics by the stream.
__global__ __launch_bounds__(256) void k_head(
    const float* __restrict__ x, const float* __restrict__ nw,
    float* __restrict__ scores_p, const float* __restrict__ cw1,
    const float* __restrict__ cw2, short* __restrict__ wA,
    short* __restrict__ wT, short* __restrict__ xb, float* __restrict__ out) {
  int blk = blockIdx.x;
  int t = threadIdx.x;
  if (blk < 512) {
    int b = blk & 31, g = blk >> 5;  // g 0..15: rows 4g..4g+3
    __shared__ float wsm[4][80];
    __shared__ alignas(16) f32x4 red4[256];
    for (int i = t; i < 300; i += 256) {
      int d = i / 75, k = i - 75 * d;
      int f = (2 << d) - 2;  // filters 0,2,6,14
      wsm[d][k] = nw[f * 75 + k];
    }
    __syncthreads();
    int p = g * 256 + t;
    int y = p >> 6, xx = p & 63;
    f32x4 s = f32x4{0.f, 0.f, 0.f, 0.f};
    for (int ic = 0; ic < INC; ic++) {
      for (int ky = 0; ky < KK; ky++) {
        int yy = y + ky - 2;
        if (yy < 0 || yy >= HH) continue;
        const float* xr = x + ((b * INC + ic) * HH + yy) * WW;
        int wk = (ic * KK + ky) * KK;
        for (int kx = 0; kx < KK; kx++) {
          int xc = xx + kx - 2;
          if (xc < 0 || xc >= WW) continue;
          float xv = xr[xc];
          s[0] = fmaf(xv, wsm[0][wk + kx], s[0]);
          s[1] = fmaf(xv, wsm[1][wk + kx], s[1]);
          s[2] = fmaf(xv, wsm[2][wk + kx], s[2]);
          s[3] = fmaf(xv, wsm[3][wk + kx], s[3]);
        }
      }
    }
    red4[t] = s;
    __syncthreads();
    for (int s2 = 128; s2 > 0; s2 >>= 1) {
      if (t < s2) {
        f32x4 a = red4[t], c = red4[t + s2];
#pragma unroll
        for (int d = 0; d < 4; d++) a[d] = fmaxf(a[d], c[d]);
        red4[t] = a;
      }
      __syncthreads();
    }
    if (t == 0) {
      f32x4 r = red4[0];
#pragma unroll
      for (int d = 0; d < 4; d++) scores_p[(d * BATCH + b) * 16 + g] = r[d];
    }
  } else if (blk < 896) {
    int idx = (blk - 512) * 256 + t;
    if (idx < 98304) {
      int k = idx % 96;
      int rem = idx / 96;  // l*64 + oc
      float v = (k < 75) ? cw1[(size_t)rem * 75 + k] : 0.f;
      wA[(size_t)rem * 96 + k] = f2bs(v);
    }
  } else if (blk < 1152) {
    int i3 = (blk - 896) * 256 + t;   // < 65536: (l, oc, ic)
    int l = i3 >> 12;
    int oc = (i3 >> 6) & 63;
    int ic = i3 & 63;
    const float* src = cw2 + (size_t)((l * OC + oc) * OC + ic) * 25;
    short* dst = wT + (size_t)oc * 64 + ic;
#pragma unroll
    for (int tap = 0; tap < 25; tap++)
      dst[((size_t)(l * 25 + tap)) * 4096] = f2bs(src[tap]);
  } else if (blk < 1382) {
    // pad+convert: job -> (img = b*3+ic, padded row 0..67, 8-short segment 0..8)
    int job = (blk - 1152) * 256 + t;
    if (job < 58752) {  // 96 * 68 * 9
      int seg = job % 9;
      int rem = job / 9;
      int row = rem % 68;
      int img = rem / 68;
      int gy = row - 2;
      short8 v;
#pragma unroll
      for (int j = 0; j < 8; j++) {
        int gx = seg * 8 + j - 2;
        float f = (gy >= 0 && gy < HH && gx >= 0 && gx < WW)
                      ? x[((size_t)img * HH + gy) * WW + gx] : 0.f;
        v[j] = f2bs(f);
      }
      *(short8*)(xb + ((size_t)img * 68 + row) * 72 + seg * 8) = v;
    }
  } else {
    for (int i = t; i < BATCH * OW; i += 256) out[i] = 0.f;
  }
}

// ---------------- conv1 via im2col + MFMA + in-register maxpool/relu -> h1t ----------------
// R29 version (verified): leaf-invariant B-fragments hoisted to 24 short8 regs;
// barrier-free shuffle epilogue.
__device__ __forceinline__ int slotbase(int col) {
  return col * 104 + 8 * ((-(col >> 1)) & 7);
}

__global__ __launch_bounds__(256, 2) void k_conv1m(
    const short* __restrict__ xb, const short* __restrict__ wA,
    short* __restrict__ h1t) {
  constexpr int BSZ = 64 * 104 + 64;
  __shared__ alignas(16) short Bm[2 * BSZ];
  int bid = blockIdx.x;
  int py = bid & 31;
  int b = bid >> 5;
  int t = threadIdx.x;
  int w = t >> 6, lane = t & 63;
  int n = lane & 15, q = lane >> 4;

  for (int i = t; i < BSZ; i += 256) ((int*)Bm)[i] = 0;
  __syncthreads();
  for (int i = t; i < 1200; i += 256) {
    int cg = i & 7;
    int kk = (i >> 3) % 75;
    int dy = (i >> 3) / 75;
    int ic = kk / 25, r25 = kk % 25;
    int ky = r25 / 5, kx = r25 % 5;
    int y = 2 * py + dy + ky;   // padded row index (halo folded in)
    const short* xr = xb + ((size_t)(b * INC + ic) * 68 + y) * 72 + kx;
    short* dst = Bm + dy * BSZ;
#pragma unroll
    for (int c8 = 0; c8 < 8; c8++) {
      int c = cg * 8 + c8;
      dst[slotbase(c) + kk] = xr[c];   // in-bounds by construction
    }
  }
  __syncthreads();   // last barrier in the kernel

  // hoist the 24 leaf-invariant B-fragments into registers (compile-time indices)
  short8 Breg[2][2][2][3];  // [dy][dx][h][ks]
#pragma unroll
  for (int dy = 0; dy < 2; dy++)
#pragma unroll
    for (int dx = 0; dx < 2; dx++)
#pragma unroll
      for (int h = 0; h < 2; h++) {
        int col = 2 * (h * 16 + n) + dx;
        const short* bp = Bm + dy * BSZ + slotbase(col);
#pragma unroll
        for (int ks = 0; ks < 3; ks++)
          Breg[dy][dx][h][ks] = *(const short8*)(bp + ks * 32 + q * 8);
      }

  short8 Acur[3], Anx[3];
#pragma unroll
  for (int ks = 0; ks < 3; ks++)
    Anx[ks] = *(const short8*)(wA + ((size_t)(w * 16 + n) * 96) + ks * 32 + q * 8);

  short* hb = h1t + ((size_t)b * (HP * WP) + py * WP) * OC;

  for (int l = 0; l < NL; l++) {
#pragma unroll
    for (int ks = 0; ks < 3; ks++) Acur[ks] = Anx[ks];
    if (l < NL - 1) {
#pragma unroll
      for (int ks = 0; ks < 3; ks++)
        Anx[ks] = *(const short8*)(wA + ((size_t)((l + 1) * OC + w * 16 + n) * 96) +
                                   ks * 32 + q * 8);
    }
    f32x4 acc[2][2][2];  // [dy][dx][half]
#pragma unroll
    for (int dy = 0; dy < 2; dy++)
#pragma unroll
      for (int dx = 0; dx < 2; dx++)
#pragma unroll
        for (int h = 0; h < 2; h++) acc[dy][dx][h] = f32x4{0.f, 0.f, 0.f, 0.f};

#pragma unroll
    for (int dy = 0; dy < 2; dy++)
#pragma unroll
      for (int dx = 0; dx < 2; dx++)
#pragma unroll
        for (int h = 0; h < 2; h++)
#pragma unroll
          for (int ks = 0; ks < 3; ks++)
            acc[dy][dx][h] = __builtin_amdgcn_mfma_f32_16x16x32_bf16(
                Acur[ks], Breg[dy][dx][h][ks], acc[dy][dx][h], 0, 0, 0);

    // barrier-free epilogue: pool+relu -> bf16 quads for h=0,1
    short4v sv0, sv1;
#pragma unroll
    for (int r = 0; r < 4; r++) {
      float v0 = fmaxf(fmaxf(acc[0][0][0][r], acc[0][1][0][r]),
                       fmaxf(acc[1][0][0][r], acc[1][1][0][r]));
      sv0[r] = f2bs(fmaxf(v0, 0.f));
      float v1 = fmaxf(fmaxf(acc[0][0][1][r], acc[0][1][1][r]),
                       fmaxf(acc[1][0][1][r], acc[1][1][1][r]));
      sv1[r] = f2bs(fmaxf(v1, 0.f));
    }
    long long l0, l1;
    memcpy(&l0, &sv0, 8);
    memcpy(&l1, &sv1, 8);
    bool hodd = (q & 1);                     // this lane keeps h = q&1
    long long own = hodd ? l1 : l0;
    long long oth = hodd ? l0 : l1;          // send the other-h payload
    long long rec = __shfl_xor(oth, 16, 64); // partner q^1's h=q&1 payload
    long long lo = hodd ? rec : own;         // even q owns the lower oc quad
    long long hi = hodd ? own : rec;
    union { short8 s; long long ll[2]; } u;
    u.ll[0] = lo; u.ll[1] = hi;
    int px = ((q & 1) << 4) + n;
    *(short8*)(hb + ((size_t)l * BATCH * (HP * WP)) * OC + (size_t)px * OC +
               16 * w + 8 * (q >> 1)) = u.s;
  }
}

// ---------------- conv2 via MFMA implicit GEMM + spatial max -> pfeat ----------------
// R20 VERBATIM (best verified: 117 us, 0 bank conflicts, VGPR 112). Twelve
// structural variants (R13-R25) all measured worse; R31's fence-fused MLP tail
// halved MfmaUtil (device fences poisoned wT/h1t L2 residency) — reverted.
__global__ __launch_bounds__(256, 2) void k_conv2m(
    const short* __restrict__ h1t, const short* __restrict__ wT,
    float* __restrict__ pfeat) {
  constexpr int CS2 = 32;          // shorts per (row,col) slot: 32 ic of chunk (64 B)
  __shared__ alignas(16) short hs[23040];     // 20 rows x 36 cols x 32 ic = 46,080 B
  __shared__ alignas(16) float sred[4][64];
  int raw = blockIdx.x;
  int bid = (raw & 7) * 128 + (raw >> 3);  // XCD swizzle (bijective: 1024/8=128)
  int half = bid & 1;
  int b = (bid >> 1) & 31;
  int l = bid >> 6;
  int t = threadIdx.x;
  int w = t >> 6, lane = t & 63;
  int n = lane & 15, q = lane >> 4;
  int y0 = half * 16;
  const short* hg = h1t + (size_t)(l * BATCH + b) * (HP * WP) * OC;
  const short* wbase = wT + (size_t)l * 25 * OC * OC;

  // per-thread staging source offsets (granule idx = i*256+t < 2880), reused per chunk.
  // Store swizzle: granule (slot, v) sources icq = (v - (cc>>1)) & 3.
  int ofsB[12];
#pragma unroll
  for (int i = 0; i < 12; i++) {
    int idx = i * 256 + t;
    int v = idx & 3;
    int cc = (idx >> 2) % 36;
    int r = (idx >> 2) / 36;          // < 20 for idx < 2880
    int icq = (v - (cc >> 1)) & 3;
    int y = y0 - 2 + r, xx = cc - 2;
    bool ok = (y >= 0) && (y < HP) && (xx >= 0) && (xx < WP);
    ofsB[i] = ok ? ((y * WP + xx) * OC + icq * 8) : -1;
  }

  f32x4 acc[4][8];  // [octile][pxtile: row(4) x colhalf(2)]
#pragma unroll
  for (int i = 0; i < 4; i++)
#pragma unroll
    for (int j = 0; j < 8; j++) acc[i][j] = f32x4{0.f, 0.f, 0.f, 0.f};

  short8 Acur[4], Anext[4];
  // A-frag: A[m=lane&15][k=q*8+j]; k = ic within current 32-chunk
#pragma unroll
  for (int oct = 0; oct < 4; oct++)
    Anext[oct] = *(const short8*)(wbase + (size_t)(oct * 16 + n) * OC + q * 8);

  for (int chunk = 0; chunk < 2; chunk++) {
    __syncthreads();  // protect hs from previous chunk's readers
    // stage: 2880 granules of 16 B via global_load_lds (linear dest, swizzled source)
#pragma unroll
    for (int i = 0; i < 12; i++) {
      if (i < 11 || t < 64) {  // idx < 2880 only
        const short* gp = (ofsB[i] < 0) ? zero16 : (hg + ofsB[i] + chunk * 32);
        __builtin_amdgcn_global_load_lds(
            (const __attribute__((address_space(1))) void*)gp,
            (__attribute__((address_space(3))) void*)&hs[(i * 256 + t) * 8],
            16, 0, 0);
      }
    }
    __syncthreads();  // compiler drains vmcnt before the barrier

    for (int tap = 0; tap < 25; tap++) {
#pragma unroll
      for (int i = 0; i < 4; i++) Acur[i] = Anext[i];
      if (!(chunk == 1 && tap == 24)) {
        int ntap = tap + 1, nch = chunk;
        if (ntap == 25) { ntap = 0; nch = 1; }
        const short* tb = wbase + (size_t)ntap * OC * OC;
#pragma unroll
        for (int oct = 0; oct < 4; oct++)
          Anext[oct] = *(const short8*)(tb + (size_t)(oct * 16 + n) * OC +
                                        nch * 32 + q * 8);
      }
      int dy = tap / 5, dx = tap - 5 * dy;
      __builtin_amdgcn_s_setprio(1);
#pragma unroll
      for (int pxt = 0; pxt < 8; pxt++) {
        int lr = 4 * w + (pxt >> 1) + dy;     // slab row 0..19
        int c = (pxt & 1) * 16 + n + dx;      // slab col 0..35
        int v = (q + (c >> 1)) & 3;           // swizzled granule within slot
        short8 B = *(const short8*)(&hs[(lr * 36 + c) * CS2 + v * 8]);
#pragma unroll
        for (int oct = 0; oct < 4; oct++)
          acc[oct][pxt] = __builtin_amdgcn_mfma_f32_16x16x32_bf16(
              Acur[oct], B, acc[oct][pxt], 0, 0, 0);
      }
      __builtin_amdgcn_s_setprio(0);
    }
  }

  // epilogue: max over this wave's 128 px; D layout: col(px)=lane&15, row(oc)=q*4+reg
#pragma unroll
  for (int oct = 0; oct < 4; oct++) {
    f32x4 m = acc[oct][0];
#pragma unroll
    for (int pxt = 1; pxt < 8; pxt++)
#pragma unroll
      for (int r = 0; r < 4; r++) m[r] = fmaxf(m[r], acc[oct][pxt][r]);
#pragma unroll
    for (int mask = 1; mask <= 8; mask <<= 1)
#pragma unroll
      for (int r = 0; r < 4; r++) m[r] = fmaxf(m[r], __shfl_xor(m[r], mask, 64));
    if (n == 0) *(f32x4*)&sred[w][oct * 16 + q * 4] = m;
  }
  __syncthreads();
  if (t < 64) {
    float m = fmaxf(fmaxf(sred[0][t], sred[1][t]), fmaxf(sred[2][t], sred[3][t]));
    pfeat[((size_t)(l * BATCH + b) * 2 + half) * OC + t] = m;
  }
}

// ---------------- per-leaf 2-layer MLP + weighted combine (atomicAdd into out) --------
// R32: R30 structure (no fences — R31's fence fusion poisoned L2) with both GEMV
// loops converted to 4-way partial sums: the old 64/128-deep dependent fma chains
// (~770 cy serial/thread) were the latency bound at 2 waves/block.
__global__ __launch_bounds__(128) void k_mlp(
    const float* __restrict__ pfeat, const float* __restrict__ w1s,
    const float* __restrict__ b1s, const float* __restrict__ w2s,
    const float* __restrict__ b2s, const float* __restrict__ scores_p,
    const float* __restrict__ nb, float* __restrict__ out) {
  __shared__ float fs[OC];
  __shared__ float hid[LW];
  int bid = blockIdx.x;
  int b = bid & 31;
  int l = bid >> 5;
  int t = threadIdx.x;
  if (t < OC) {
    const float* pf = pfeat + (size_t)(l * BATCH + b) * 2 * OC;
    fs[t] = fmaxf(fmaxf(pf[t], pf[OC + t]), 0.f);  // relu(global max)
  }
  __syncthreads();
  {
    float h0 = b1s[l * LW + t], h1 = 0.f, h2 = 0.f, h3 = 0.f;
    const float* wb1 = w1s + (size_t)l * OC * LW + t;
#pragma unroll 4
    for (int c = 0; c < OC; c += 4) {
      h0 = fmaf(fs[c + 0], wb1[(c + 0) * LW], h0);
      h1 = fmaf(fs[c + 1], wb1[(c + 1) * LW], h1);
      h2 = fmaf(fs[c + 2], wb1[(c + 2) * LW], h2);
      h3 = fmaf(fs[c + 3], wb1[(c + 3) * LW], h3);
    }
    hid[t] = (h0 + h1) + (h2 + h3);
  }
  __syncthreads();
  if (t < OW) {
    // mix weight for (b, l) — 16 fmax + 4 sigmoid, redundant per thread
    float mix = 1.f;
#pragma unroll
    for (int d = 0; d < 4; d++) {
      const float* sp = scores_p + (d * BATCH + b) * 16;
      float sc = sp[0];
#pragma unroll
      for (int g = 1; g < 16; g++) sc = fmaxf(sc, sp[g]);
      int j = l >> (3 - d);
      int i = j >> 1;
      int bit = j & 1;
      float z = sc + nb[(1 << d) - 1 + i];
      float be = 1.f / (1.f + expf(-z));
      mix *= bit ? be : (1.f - be);
    }
    float o0 = b2s[l * OW + t], o1 = 0.f, o2 = 0.f, o3 = 0.f;
    const float* wb2 = w2s + (size_t)l * LW * OW + t;
#pragma unroll 4
    for (int j = 0; j < LW; j += 4) {
      o0 = fmaf(hid[j + 0], wb2[(j + 0) * OW], o0);
      o1 = fmaf(hid[j + 1], wb2[(j + 1) * OW], o1);
      o2 = fmaf(hid[j + 2], wb2[(j + 2) * OW], o2);
      o3 = fmaf(hid[j + 3], wb2[(j + 3) * OW], o3);
    }
    atomicAdd(&out[b * OW + t], mix * ((o0 + o1) + (o2 + o3)));
  }
}

extern "C" void kernel_launch(void* const* d_in, const int* in_sizes, int n_in,
                              void* d_out, int out_size, void* d_ws, size_t ws_size,
                              hipStream_t stream) {
  const float* x   = (const float*)d_in[0];
  const float* nw  = (const float*)d_in[1];
  const float* nb  = (const float*)d_in[2];
  const float* cw1 = (const float*)d_in[3];
  const float* cw2 = (const float*)d_in[4];
  const float* w1s = (const float*)d_in[5];
  const float* b1s = (const float*)d_in[6];
  const float* w2s = (const float*)d_in[7];
  const float* b2s = (const float*)d_in[8];
  float* out = (float*)d_out;

  char* ws = (char*)d_ws;
  short* h1t = (short*)ws;  // [l,b][px 1024][ic 64] bf16 = 67.1 MB
  size_t off = (size_t)NL * BATCH * HP * WP * OC * sizeof(short);
  short* wT = (short*)(ws + off); off += (size_t)NL * 25 * OC * OC * sizeof(short);
  short* wA = (short*)(ws + off); off += (size_t)NL * OC * 96 * sizeof(short);
  short* xb = (short*)(ws + off); off += (size_t)96 * 68 * 72 * sizeof(short);
  float* scores_p = (float*)(ws + off); off += 4 * BATCH * 16 * sizeof(float);
  float* pfeat  = (float*)(ws + off); off += (size_t)NL * BATCH * 2 * OC * sizeof(float);
  (void)ws_size; (void)in_sizes; (void)n_in; (void)out_size;

  k_head<<<1383, 256, 0, stream>>>(x, nw, scores_p, cw1, cw2, wA, wT, xb, out);
  k_conv1m<<<BATCH * 32, 256, 0, stream>>>(xb, wA, h1t);
  k_conv2m<<<NL * BATCH * 2, 256, 0, stream>>>(h1t, wT, pfeat);
  k_mlp<<<NL * BATCH, 128, 0, stream>>>(pfeat, w1s, b1s, w2s, b2s, scores_p, nb, out);
}